// Round 5
// baseline (319.755 us; speedup 1.0000x reference)
//
#include <hip/hip_runtime.h>

// ScaledDotProductAttention winner-take-all (B=16, Lq=Lk=2048, D=64, fp32).
// attn = softmax(QK^T/8); mask = (attn == rowmax); attn *= mask; out = attn@V.
// Post-mask attn has ~1 nonzero/row -> QK^T + online top-2 + Z only.
//
// R5: R4 structure (NT=512 -> 16 waves/CU, in-register Q split, K-only
// fragment prepass) but with REGULAR stores (nt bypassed L2 write path and
// regressed ~18us) and the 1-deep K-fragment register prefetch restored.

namespace {
constexpr int LQn = 2048, LKn = 2048, Dn = 64;
constexpr int QB  = 64;            // q rows per block
constexpr int NT  = 512;           // 8 waves: (q-group x k-quarter)
constexpr float K1 = 0.125f * 1.44269504088896340736f;  // exp(s/8-10)=exp2(..)
constexpr float K2 = 10.0f  * 1.44269504088896340736f;
constexpr float CSC = 1.0f / 4096.0f;   // cross-term descale
}

typedef _Float16 half8  __attribute__((ext_vector_type(8)));
typedef float    f32x16 __attribute__((ext_vector_type(16)));

// ---------------- pre-pass: K fp32 -> (hi, lo*4096) fp16 fragments ----------
// Layout: khl[(b*64 + grp)*8 + c][lane][8 f16]; c<4: hi chunk c, c>=4: lo.
// Fragment semantics (32x32x16): lane l supplies row (l&31), dims
// c4*16 + (l>>5)*8 + e (same formula for A and B -> k-permutation cancels).
__global__ __launch_bounds__(256)
void split_pack_k(const float* __restrict__ src_k, half8* __restrict__ khl) {
  const int t = threadIdx.x, l = t & 63, w = t >> 6;
  const int gid = blockIdx.x * 4 + w;          // 0..1023
  const int b = gid >> 6, grp = gid & 63;
  const float* src = src_k + ((size_t)b * 2048 + grp * 32 + (l & 31)) * Dn;
  half8* dst = khl + ((size_t)(b * 64 + grp) * 8) * 64 + l;
  const int dhalf = (l >> 5) * 8;
  #pragma unroll
  for (int c4 = 0; c4 < 4; ++c4) {
    const float* s8 = src + c4 * 16 + dhalf;
    float4 x0 = *(const float4*)s8;
    float4 x1 = *(const float4*)(s8 + 4);
    float xs[8] = {x0.x, x0.y, x0.z, x0.w, x1.x, x1.y, x1.z, x1.w};
    half8 hh, ll;
    #pragma unroll
    for (int e = 0; e < 8; ++e) {
      float x = xs[e];
      _Float16 h = (_Float16)x;
      float r = x - (float)h;                  // exact
      hh[e] = h;
      ll[e] = (_Float16)(r * 4096.0f);         // normalized, no f16 denorm
    }
    dst[(size_t)c4 * 64]       = hh;
    dst[(size_t)(4 + c4) * 64] = ll;
  }
}

// ---------------- main: MFMA QK^T + online top-2 + Z ------------------------
__global__ __launch_bounds__(NT, 4)
void attn_wta_mfma(const float* __restrict__ qg, const half8* __restrict__ khl,
                   const float* __restrict__ vg, float* __restrict__ out_o,
                   float* __restrict__ out_a) {
  __shared__ float em_s[256], es_s[256], zz_s[256];
  __shared__ int   p1_s[256], p2_s[256];
  __shared__ float rowP[QB];
  __shared__ int   rW1[QB], rW2[QB];

  const int t = threadIdx.x, l = t & 63, w = t >> 6;
  const int hi = l >> 5;
  const int qg2 = w & 1;             // q-group within tile (32 rows)
  const int kq  = w >> 1;            // k quarter (512 rows = 16 tiles)

  // XCD-bijective swizzle (512 % 8 == 0): 64 consecutive wgs/XCD = 2 batches.
  const int wg  = (int)blockIdx.x;
  const int swz = (wg & 7) * 64 + (wg >> 3);
  const int bb  = swz >> 5;          // batch
  const int q0  = (swz & 31) * QB;   // q-tile base row

  // ---- Q fragments built in-register: lane l owns q-row (l&31) of group ----
  half8 qf[8];
  {
    const float* qsrc = qg + ((size_t)bb * LQn + q0 + qg2 * 32 + (l & 31)) * Dn
                        + hi * 8;
    #pragma unroll
    for (int c4 = 0; c4 < 4; ++c4) {
      float4 x0 = *(const float4*)(qsrc + c4 * 16);
      float4 x1 = *(const float4*)(qsrc + c4 * 16 + 4);
      float xs[8] = {x0.x, x0.y, x0.z, x0.w, x1.x, x1.y, x1.z, x1.w};
      half8 hh, ll;
      #pragma unroll
      for (int e = 0; e < 8; ++e) {
        float x = xs[e];
        _Float16 h = (_Float16)x;
        float r = x - (float)h;
        hh[e] = h;
        ll[e] = (_Float16)(r * 4096.0f);
      }
      qf[c4]     = hh;
      qf[4 + c4] = ll;
    }
  }

  float em = -1.0f, es = -1.0f, zz = 0.0f;
  int   p1 = 0, p2 = 0;

  const half8* kp = khl + (((size_t)bb * 64 + kq * 16) * 8) * 64 + l;
  float* oa = out_a + ((size_t)bb * LQn + q0) * (size_t)LKn;
  const float4 z4 = make_float4(0.f, 0.f, 0.f, 0.f);

  // 1-deep register prefetch of k-tile fragments
  half8 af[8];
  #pragma unroll
  for (int c = 0; c < 8; ++c) af[c] = kp[(size_t)c * 64];

  #pragma unroll 1
  for (int it = 0; it < 16; ++it) {
    // prefetch next k-tile fragments (registers)
    half8 an[8];
    {
      int nx = it + 1 < 16 ? it + 1 : 15;
      const half8* np_ = kp + (size_t)nx * 8 * 64;
      #pragma unroll
      for (int c = 0; c < 8; ++c) an[c] = np_[(size_t)c * 64];
    }
    // zero-fill slice of attn region (regular stores -> L2 write path; drains
    // under compute, ordered before winner scatter by the post-loop barrier)
    #pragma unroll
    for (int j = 0; j < 4; ++j) {
      int f = it * 2048 + j * 512 + t;         // 32768 float4 = 64 x 2048
      *(float4*)(oa + (size_t)f * 4) = z4;
    }
    // 12 MFMAs: hh -> ah ; (hi*lo' + lo'*hi) -> ac (descaled by 2^-12 later)
    f32x16 ah, ac;
    #pragma unroll
    for (int r = 0; r < 16; ++r) { ah[r] = 0.0f; ac[r] = 0.0f; }
    #pragma unroll
    for (int c4 = 0; c4 < 4; ++c4) {
      ah = __builtin_amdgcn_mfma_f32_32x32x16_f16(af[c4],     qf[c4],     ah, 0, 0, 0);
      ac = __builtin_amdgcn_mfma_f32_32x32x16_f16(af[c4],     qf[4 + c4], ac, 0, 0, 0);
      ac = __builtin_amdgcn_mfma_f32_32x32x16_f16(af[4 + c4], qf[c4],     ac, 0, 0, 0);
    }
    // fold 16 lane-local scores (this lane's q-column) into top-2 + Z
    const int kbase = (kq * 16 + it) * 32;
    #pragma unroll
    for (int r = 0; r < 16; ++r) {
      float s = fmaf(ac[r], CSC, ah[r]);
      float e = exp2f(fmaf(s, K1, -K2));
      int pos = kbase + (r & 3) + 8 * (r >> 2) + 4 * hi;
      bool g1 = e > em, g2 = e > es;
      es = g1 ? em : (g2 ? e : es);
      p2 = g1 ? p1 : (g2 ? pos : p2);
      em = g1 ? e : em;
      p1 = g1 ? pos : p1;
      zz += e;
    }
    #pragma unroll
    for (int c = 0; c < 8; ++c) af[c] = an[c];
  }

  // merge lane pairs (l, l+32): same q-column, disjoint k rows
  {
    float oem = __shfl_xor(em, 32, 64);
    float oes = __shfl_xor(es, 32, 64);
    float ozz = __shfl_xor(zz, 32, 64);
    int   op1 = __shfl_xor(p1, 32, 64);
    int   op2 = __shfl_xor(p2, 32, 64);
    zz += ozz;
    bool g1 = oem > em, g2 = oem > es;
    es = g1 ? em : (g2 ? oem : es);
    p2 = g1 ? p1 : (g2 ? op1 : p2);
    em = g1 ? oem : em;
    p1 = g1 ? op1 : p1;
    bool h2 = oes > es;
    es = h2 ? oes : es;
    p2 = h2 ? op2 : p2;
  }
  if (l < 32) {
    int idx = w * 32 + l;                      // w = qg2 + 2*kq
    em_s[idx] = em; es_s[idx] = es; zz_s[idx] = zz;
    p1_s[idx] = p1; p2_s[idx] = p2;
  }
  __syncthreads();   // also drains all zero-fill stores (vmcnt 0)

  if (t < QB) {
    const int g = t >> 5, q = t & 31;
    float m1 = -1.0f, m2 = -1.0f, Z = 0.0f;
    int w1 = 0, w2 = 0;
    #pragma unroll
    for (int k4 = 0; k4 < 4; ++k4) {
      int idx = (g + 2 * k4) * 32 + q;
      float a1 = em_s[idx], a2 = es_s[idx];
      int pa1 = p1_s[idx], pa2 = p2_s[idx];
      Z += zz_s[idx];
      bool lead = a1 > m1;
      bool t2a  = m1 > a2;              // if lead: second = max(old m1, a2)
      bool t2b  = a1 > m2;              // else:    second = max(m2, a1)
      float nm2 = lead ? (t2a ? m1 : a2) : (t2b ? a1 : m2);
      int   nw2 = lead ? (t2a ? w1 : pa2) : (t2b ? pa1 : w2);
      m1 = lead ? a1 : m1;
      w1 = lead ? pa1 : w1;
      m2 = nm2; w2 = nw2;
    }
    float p  = m1 / Z;
    float ps = m2 / Z;
    int wsec = (ps == p) ? w2 : -1;     // prob-level tie, like reference
    rowP[t] = p; rW1[t] = w1; rW2[t] = wsec;
    float* ar = oa + (size_t)t * LKn;
    ar[w1] = p;
    if (wsec >= 0) ar[wsec] = p;
  }
  __syncthreads();

  // output rows: out[r,:] = p * v[w1,:] (+ p * v[w2,:])
  const float* vb = vg + (size_t)bb * LKn * Dn;
  float* oo = out_o + ((size_t)bb * LQn + q0) * Dn;
  #pragma unroll
  for (int j = 0; j < 2; ++j) {
    int slot = j * NT + t;               // 1024 slots = 64 rows x 16 float4
    int r = slot >> 4, c4 = slot & 15;
    float p = rowP[r];
    int w1 = rW1[r], w2 = rW2[r];
    float4 v1 = *(const float4*)(vb + (size_t)w1 * Dn + c4 * 4);
    float4 o = make_float4(p * v1.x, p * v1.y, p * v1.z, p * v1.w);
    if (w2 >= 0) {
      float4 v2 = *(const float4*)(vb + (size_t)w2 * Dn + c4 * 4);
      o.x += p * v2.x; o.y += p * v2.y; o.z += p * v2.z; o.w += p * v2.w;
    }
    *(float4*)(oo + (size_t)r * Dn + c4 * 4) = o;
  }
}

// ---------------- fallback (proven R1 kernel) if ws too small ---------------
__global__ __launch_bounds__(256, 2)
void attn_wta_fp32(const float* __restrict__ qg, const float* __restrict__ kg,
                   const float* __restrict__ vg, float* __restrict__ out_o,
                   float* __restrict__ out_a) {
  __shared__ float4 k_s[256][16];
  __shared__ float  q_s[64][64];
  float* rowP  = &q_s[0][0];
  int*   rPos1 = (int*)&q_s[1][0];
  int*   rPos2 = (int*)&q_s[2][0];
  const int t = threadIdx.x, tx = t & 31, ty = t >> 5;
  const int wg = (int)blockIdx.x;
  const int swz = (wg & 7) * 64 + (wg >> 3);
  const int bb = swz >> 5, q0 = (swz & 31) * 64;
  const float* qb = qg + ((size_t)bb * LQn + q0) * Dn;
  const float* kb = kg + (size_t)bb * LKn * Dn;
  const float* vb = vg + (size_t)bb * LKn * Dn;
  float* oa = out_a + ((size_t)bb * LQn + q0) * (size_t)LKn;
  float* oo = out_o + ((size_t)bb * LQn + q0) * Dn;
  #pragma unroll
  for (int it = 0; it < 4; ++it) {
    int slot = it * 256 + t, r = slot >> 4, c4 = slot & 15;
    *(float4*)&q_s[r][c4 * 4] = *(const float4*)(qb + r * Dn + c4 * 4);
  }
  float emax[8], e2nd[8], zsum[8]; int pos1[8], pos2[8];
  #pragma unroll
  for (int i = 0; i < 8; ++i) { emax[i] = -1.f; e2nd[i] = -1.f; zsum[i] = 0.f; pos1[i] = 0; pos2[i] = 0; }
  float* zbase = oa + (size_t)(t >> 6) * LKn + (t & 63) * 4;
  #pragma unroll 1
  for (int kt = 0; kt < 8; ++kt) {
    __syncthreads();
    const float* ksrc = kb + (size_t)kt * 256 * Dn;
    #pragma unroll
    for (int it = 0; it < 16; ++it) {
      int slot = it * 256 + t, r = slot >> 4, c4 = slot & 15;
      k_s[r][c4 ^ (r & 7)] = *(const float4*)(ksrc + r * Dn + c4 * 4);
    }
    __syncthreads();
    float4 z4 = make_float4(0.f, 0.f, 0.f, 0.f);
    float* zp = zbase + (size_t)kt * 256;
    #pragma unroll
    for (int it = 0; it < 16; ++it) *(float4*)(zp + (size_t)it * 4 * LKn) = z4;
    float acc[8][8];
    #pragma unroll
    for (int i = 0; i < 8; ++i)
      #pragma unroll
      for (int j = 0; j < 8; ++j) acc[i][j] = 0.f;
    #pragma unroll 4
    for (int dc = 0; dc < 16; ++dc) {
      float4 qv[8], kv[8];
      #pragma unroll
      for (int i = 0; i < 8; ++i) qv[i] = *(const float4*)&q_s[ty * 8 + i][dc * 4];
      const int csw = dc ^ (tx & 7);
      #pragma unroll
      for (int j = 0; j < 8; ++j) kv[j] = k_s[j * 32 + tx][csw];
      #pragma unroll
      for (int i = 0; i < 8; ++i)
        #pragma unroll
        for (int j = 0; j < 8; ++j) {
          acc[i][j] = fmaf(qv[i].x, kv[j].x, acc[i][j]);
          acc[i][j] = fmaf(qv[i].y, kv[j].y, acc[i][j]);
          acc[i][j] = fmaf(qv[i].z, kv[j].z, acc[i][j]);
          acc[i][j] = fmaf(qv[i].w, kv[j].w, acc[i][j]);
        }
    }
    const int kt0 = kt * 256;
    #pragma unroll
    for (int i = 0; i < 8; ++i) {
      float em = emax[i], es = e2nd[i], zq = zsum[i];
      int p1 = pos1[i], p2 = pos2[i];
      #pragma unroll
      for (int j = 0; j < 8; ++j) {
        float e = exp2f(fmaf(acc[i][j], K1, -K2));
        int pos = kt0 + j * 32 + tx;
        bool g1 = e > em, g2 = e > es;
        es = g1 ? em : (g2 ? e : es);
        p2 = g1 ? p1 : (g2 ? pos : p2);
        em = g1 ? e : em;
        p1 = g1 ? pos : p1;
        zq += e;
      }
      emax[i] = em; e2nd[i] = es; zsum[i] = zq; pos1[i] = p1; pos2[i] = p2;
    }
  }
  #pragma unroll
  for (int i = 0; i < 8; ++i) {
    float em = emax[i], es = e2nd[i], zq = zsum[i];
    int p1 = pos1[i], p2 = pos2[i];
    #pragma unroll
    for (int m = 16; m >= 1; m >>= 1) {
      float oem = __shfl_xor(em, m); float oes = __shfl_xor(es, m);
      float ozz = __shfl_xor(zq, m);
      int op1 = __shfl_xor(p1, m); int op2 = __shfl_xor(p2, m);
      zq += ozz;
      bool g1 = oem > em, g2 = oem > es;
      es = g1 ? em : (g2 ? oem : es);
      p2 = g1 ? p1 : (g2 ? op1 : p2);
      em = g1 ? oem : em; p1 = g1 ? op1 : p1;
      bool h2 = oes > es;
      es = h2 ? oes : es; p2 = h2 ? op2 : p2;
    }
    emax[i] = em; e2nd[i] = es; zsum[i] = zq; pos1[i] = p1; pos2[i] = p2;
  }
  __syncthreads();
  if (tx == 0) {
    #pragma unroll
    for (int i = 0; i < 8; ++i) {
      int r = ty * 8 + i;
      float p = emax[i] / zsum[i], p2v = e2nd[i] / zsum[i];
      rowP[r] = p; rPos1[r] = pos1[i]; rPos2[r] = (p2v == p) ? pos2[i] : -1;
    }
  }
  __syncthreads();
  if (t < 64) {
    float p = rowP[t];
    float* ar = oa + (size_t)t * LKn;
    ar[rPos1[t]] = p;
    if (rPos2[t] >= 0) ar[rPos2[t]] = p;
  }
  #pragma unroll
  for (int it = 0; it < 4; ++it) {
    int slot = it * 256 + t, r = slot >> 4, c4 = slot & 15;
    float p = rowP[r];
    int w1 = rPos1[r], w2 = rPos2[r];
    float4 v1 = *(const float4*)(vb + (size_t)w1 * Dn + c4 * 4);
    float4 o = make_float4(p * v1.x, p * v1.y, p * v1.z, p * v1.w);
    if (w2 >= 0) {
      float4 v2 = *(const float4*)(vb + (size_t)w2 * Dn + c4 * 4);
      o.x += p * v2.x; o.y += p * v2.y; o.z += p * v2.z; o.w += p * v2.w;
    }
    *(float4*)(oo + (size_t)r * Dn + c4 * 4) = o;
  }
}

extern "C" void kernel_launch(void* const* d_in, const int* in_sizes, int n_in,
                              void* d_out, int out_size, void* d_ws, size_t ws_size,
                              hipStream_t stream) {
  const float* q = (const float*)d_in[0];
  const float* k = (const float*)d_in[1];
  const float* v = (const float*)d_in[2];
  float* out_o = (float*)d_out;                                  // [16,2048,64]
  float* out_a = (float*)d_out + (size_t)16 * 2048 * 64;         // [16,2048,2048]
  if (ws_size >= (size_t)8388608) {
    half8* khl = (half8*)d_ws;                                   // 8 MB
    hipLaunchKernelGGL(split_pack_k, dim3(256), dim3(256), 0, stream, k, khl);
    hipLaunchKernelGGL(attn_wta_mfma, dim3(512), dim3(NT), 0, stream,
                       q, khl, v, out_o, out_a);
  } else {
    hipLaunchKernelGGL(attn_wta_fp32, dim3(512), dim3(256), 0, stream,
                       q, k, v, out_o, out_a);
  }
}

// Round 6
// 314.005 us; speedup vs baseline: 1.0183x; 1.0183x over previous
//
#include <hip/hip_runtime.h>

// ScaledDotProductAttention winner-take-all (B=16, Lq=Lk=2048, D=64, fp32).
// attn = softmax(QK^T/8); mask = (attn == rowmax); attn *= mask; out = attn@V.
// Post-mask attn has ~1 nonzero/row -> QK^T + online top-2 + Z only.
//
// R6: R3 attn geometry (NT=256, 2qg x 2kh, 32 iters, bounds(256,2), 1-deep
// prefetch with 256-reg headroom) + K-only prepass + in-register Q split.
// NEW: ILP-restructured fold — top-2 tracked on raw scores (exp deferred to
// epilogue), 4 parallel groups of 4 + merges; Z as independent exp+add tree.

namespace {
constexpr int LQn = 2048, LKn = 2048, Dn = 64;
constexpr int QB  = 64;            // q rows per block
constexpr int NT  = 256;           // 4 waves: (q-group x k-half)
constexpr float K1 = 0.125f * 1.44269504088896340736f;  // exp(s/8-10)=exp2(..)
constexpr float K2 = 10.0f  * 1.44269504088896340736f;
constexpr float CSC  = 1.0f / 4096.0f;  // cross-term descale
constexpr float NEGI = -3.0e38f;
}

typedef _Float16 half8  __attribute__((ext_vector_type(8)));
typedef float    f32x16 __attribute__((ext_vector_type(16)));

// ---------------- pre-pass: K fp32 -> (hi, lo*4096) fp16 fragments ----------
// Layout: khl[(b*64 + grp)*8 + c][lane][8 f16]; c<4: hi chunk c, c>=4: lo.
// Fragment semantics (32x32x16): lane l supplies row (l&31), dims
// c4*16 + (l>>5)*8 + e (same formula for A and B -> k-permutation cancels).
__global__ __launch_bounds__(256)
void split_pack_k(const float* __restrict__ src_k, half8* __restrict__ khl) {
  const int t = threadIdx.x, l = t & 63, w = t >> 6;
  const int gid = blockIdx.x * 4 + w;          // 0..1023
  const int b = gid >> 6, grp = gid & 63;
  const float* src = src_k + ((size_t)b * 2048 + grp * 32 + (l & 31)) * Dn;
  half8* dst = khl + ((size_t)(b * 64 + grp) * 8) * 64 + l;
  const int dhalf = (l >> 5) * 8;
  #pragma unroll
  for (int c4 = 0; c4 < 4; ++c4) {
    const float* s8 = src + c4 * 16 + dhalf;
    float4 x0 = *(const float4*)s8;
    float4 x1 = *(const float4*)(s8 + 4);
    float xs[8] = {x0.x, x0.y, x0.z, x0.w, x1.x, x1.y, x1.z, x1.w};
    half8 hh, ll;
    #pragma unroll
    for (int e = 0; e < 8; ++e) {
      float x = xs[e];
      _Float16 h = (_Float16)x;
      float r = x - (float)h;                  // exact
      hh[e] = h;
      ll[e] = (_Float16)(r * 4096.0f);         // normalized, no f16 denorm
    }
    dst[(size_t)c4 * 64]       = hh;
    dst[(size_t)(4 + c4) * 64] = ll;
  }
}

// ---------------- main: MFMA QK^T + online top-2 + Z ------------------------
__global__ __launch_bounds__(NT, 2)
void attn_wta_mfma(const float* __restrict__ qg, const half8* __restrict__ khl,
                   const float* __restrict__ vg, float* __restrict__ out_o,
                   float* __restrict__ out_a) {
  __shared__ float em_s[128], es_s[128], zz_s[128];
  __shared__ int   p1_s[128], p2_s[128];
  __shared__ float rowP[QB];
  __shared__ int   rW1[QB], rW2[QB];

  const int t = threadIdx.x, l = t & 63, w = t >> 6;
  const int hi = l >> 5;
  const int qg2 = w & 1;             // q-group within tile (32 rows)
  const int kh2 = w >> 1;            // k half (1024 rows = 32 tiles)

  // XCD-bijective swizzle (512 % 8 == 0): 64 consecutive wgs/XCD = 2 batches.
  const int wg  = (int)blockIdx.x;
  const int swz = (wg & 7) * 64 + (wg >> 3);
  const int bb  = swz >> 5;          // batch
  const int q0  = (swz & 31) * QB;   // q-tile base row

  // ---- Q fragments built in-register: lane l owns q-row (l&31) of group ----
  half8 qf[8];
  {
    const float* qsrc = qg + ((size_t)bb * LQn + q0 + qg2 * 32 + (l & 31)) * Dn
                        + hi * 8;
    #pragma unroll
    for (int c4 = 0; c4 < 4; ++c4) {
      float4 x0 = *(const float4*)(qsrc + c4 * 16);
      float4 x1 = *(const float4*)(qsrc + c4 * 16 + 4);
      float xs[8] = {x0.x, x0.y, x0.z, x0.w, x1.x, x1.y, x1.z, x1.w};
      half8 hh, ll;
      #pragma unroll
      for (int e = 0; e < 8; ++e) {
        float x = xs[e];
        _Float16 h = (_Float16)x;
        float r = x - (float)h;
        hh[e] = h;
        ll[e] = (_Float16)(r * 4096.0f);
      }
      qf[c4]     = hh;
      qf[4 + c4] = ll;
    }
  }

  float em = NEGI, es = NEGI, zz = 0.0f;   // em/es are SCORES (exp deferred)
  int   p1 = 0, p2 = 0;

  const half8* kp = khl + (((size_t)bb * 64 + kh2 * 32) * 8) * 64 + l;
  float* oa = out_a + ((size_t)bb * LQn + q0) * (size_t)LKn;
  const float4 z4 = make_float4(0.f, 0.f, 0.f, 0.f);

  // 1-deep register prefetch of k-tile fragments
  half8 af[8];
  #pragma unroll
  for (int c = 0; c < 8; ++c) af[c] = kp[(size_t)c * 64];

  #pragma unroll 1
  for (int it = 0; it < 32; ++it) {
    // prefetch next k-tile fragments (loads BEFORE stores: counted vmcnt for
    // these loads never forces the store queue to drain)
    half8 an[8];
    {
      int nx = it + 1 < 32 ? it + 1 : 31;
      const half8* np_ = kp + (size_t)nx * 8 * 64;
      #pragma unroll
      for (int c = 0; c < 8; ++c) an[c] = np_[(size_t)c * 64];
    }
    // zero-fill slice of attn region (drains under compute; ordered before
    // winner scatter by the post-loop barrier)
    #pragma unroll
    for (int j = 0; j < 4; ++j) {
      int f = it * 1024 + j * 256 + t;         // 32768 float4 = 64 x 2048
      *(float4*)(oa + (size_t)f * 4) = z4;
    }
    // 12 MFMAs: hh -> ah ; (hi*lo' + lo'*hi) -> ac (descaled by 2^-12)
    f32x16 ah, ac;
    #pragma unroll
    for (int r = 0; r < 16; ++r) { ah[r] = 0.0f; ac[r] = 0.0f; }
    #pragma unroll
    for (int c4 = 0; c4 < 4; ++c4) {
      ah = __builtin_amdgcn_mfma_f32_32x32x16_f16(af[c4],     qf[c4],     ah, 0, 0, 0);
      ac = __builtin_amdgcn_mfma_f32_32x32x16_f16(af[c4],     qf[4 + c4], ac, 0, 0, 0);
      ac = __builtin_amdgcn_mfma_f32_32x32x16_f16(af[4 + c4], qf[c4],     ac, 0, 0, 0);
    }
    float sc[16];
    #pragma unroll
    for (int r = 0; r < 16; ++r) sc[r] = fmaf(ac[r], CSC, ah[r]);

    // ---- Z stream: independent exp + add tree ----
    float ex[16];
    #pragma unroll
    for (int r = 0; r < 16; ++r) ex[r] = exp2f(fmaf(sc[r], K1, -K2));
    #pragma unroll
    for (int rr = 8; rr >= 1; rr >>= 1)
      #pragma unroll
      for (int r = 0; r < 8; ++r)
        if (r < rr) ex[r] = ex[r] + ex[r + rr];
    zz += ex[0];

    // ---- top-2 of 16 scores: 4 parallel groups of 4, then merges ----
    float m1g[4], m2g[4]; int j1g[4], j2g[4];
    #pragma unroll
    for (int g = 0; g < 4; ++g) {
      int base = g * 4;
      float a1 = sc[base], a2 = NEGI;
      int   b1 = base,     b2 = base;
      #pragma unroll
      for (int e = 1; e < 4; ++e) {
        float v = sc[base + e];
        bool ga = v > a1, gb = v > a2;
        a2 = ga ? a1 : (gb ? v : a2);
        b2 = ga ? b1 : (gb ? base + e : b2);
        a1 = ga ? v : a1;
        b1 = ga ? base + e : b1;
      }
      m1g[g] = a1; m2g[g] = a2; j1g[g] = b1; j2g[g] = b2;
    }
    // pairwise merge (0,1) and (2,3), then final merge
    float M1[2], M2[2]; int J1[2], J2[2];
    #pragma unroll
    for (int g = 0; g < 2; ++g) {
      float A1 = m1g[2*g], A2 = m2g[2*g], B1 = m1g[2*g+1], B2 = m2g[2*g+1];
      int   a1 = j1g[2*g], a2 = j2g[2*g], b1 = j1g[2*g+1], b2 = j2g[2*g+1];
      bool x = B1 > A1;
      float c1 = x ? A1 : B1;  int cj1 = x ? a1 : b1;
      float c2 = x ? B2 : A2;  int cj2 = x ? b2 : a2;
      bool y = c2 > c1;
      M1[g] = x ? B1 : A1;     J1[g] = x ? b1 : a1;
      M2[g] = y ? c2 : c1;     J2[g] = y ? cj2 : cj1;
    }
    float iM1, iM2; int iJ1, iJ2;
    {
      bool x = M1[1] > M1[0];
      float c1 = x ? M1[0] : M1[1];  int cj1 = x ? J1[0] : J1[1];
      float c2 = x ? M2[1] : M2[0];  int cj2 = x ? J2[1] : J2[0];
      bool y = c2 > c1;
      iM1 = x ? M1[1] : M1[0];       iJ1 = x ? J1[1] : J1[0];
      iM2 = y ? c2 : c1;             iJ2 = y ? cj2 : cj1;
    }
    // local j -> global k position
    const int kbase = (kh2 * 32 + it) * 32;
    int gp1 = kbase + (iJ1 & 3) + 8 * (iJ1 >> 2) + 4 * hi;
    int gp2 = kbase + (iJ2 & 3) + 8 * (iJ2 >> 2) + 4 * hi;
    // merge iter top-2 into running top-2
    {
      bool g1 = iM1 > em, gx = iM1 > es;
      bool u  = iM2 > em;
      float t1 = u ? iM2 : em;  int tp1 = u ? gp2 : p1;
      es = g1 ? t1 : (gx ? iM1 : es);
      p2 = g1 ? tp1 : (gx ? gp1 : p2);
      em = g1 ? iM1 : em;
      p1 = g1 ? gp1 : p1;
    }
    #pragma unroll
    for (int c = 0; c < 8; ++c) af[c] = an[c];
  }

  // merge lane pairs (l, l+32): same q-column, disjoint k rows
  {
    float oem = __shfl_xor(em, 32, 64);
    float oes = __shfl_xor(es, 32, 64);
    float ozz = __shfl_xor(zz, 32, 64);
    int   op1 = __shfl_xor(p1, 32, 64);
    int   op2 = __shfl_xor(p2, 32, 64);
    zz += ozz;
    bool g1 = oem > em, g2 = oem > es;
    es = g1 ? em : (g2 ? oem : es);
    p2 = g1 ? p1 : (g2 ? op1 : p2);
    em = g1 ? oem : em;
    p1 = g1 ? op1 : p1;
    bool h2 = oes > es;
    es = h2 ? oes : es;
    p2 = h2 ? op2 : p2;
  }
  if (l < 32) {
    int idx = w * 32 + l;                      // w = qg2 + 2*kh2
    em_s[idx] = em; es_s[idx] = es; zz_s[idx] = zz;
    p1_s[idx] = p1; p2_s[idx] = p2;
  }
  __syncthreads();   // also drains all zero-fill stores (vmcnt 0)

  if (t < QB) {
    int g = t >> 5, q = t & 31;
    int ia = g * 32 + q;          // wave g   : k rows 0..1023
    int ib = (2 + g) * 32 + q;    // wave 2+g : k rows 1024..2047
    float ema = em_s[ia], esa = es_s[ia], emb = em_s[ib], esb = es_s[ib];
    float Z = zz_s[ia] + zz_s[ib];
    int pa1 = p1_s[ia], pa2 = p2_s[ia], pb1 = p1_s[ib], pb2 = p2_s[ib];
    float m1, m2; int w1, w2;
    if (emb > ema) {
      m1 = emb; w1 = pb1;
      m2 = (ema > esb) ? ema : esb; w2 = (ema > esb) ? pa1 : pb2;
    } else {
      m1 = ema; w1 = pa1;
      m2 = (emb > esa) ? emb : esa; w2 = (emb > esa) ? pb1 : pa2;
    }
    float e1 = exp2f(fmaf(m1, K1, -K2));       // exp deferred to here
    float e2 = exp2f(fmaf(m2, K1, -K2));
    float p  = e1 / Z;
    float ps = e2 / Z;
    int wsec = (ps == p) ? w2 : -1;  // prob-level tie, like reference
    rowP[t] = p; rW1[t] = w1; rW2[t] = wsec;
    float* ar = oa + (size_t)t * LKn;
    ar[w1] = p;
    if (wsec >= 0) ar[wsec] = p;
  }
  __syncthreads();

  // output rows: out[r,:] = p * v[w1,:] (+ p * v[w2,:])
  const float* vb = vg + (size_t)bb * LKn * Dn;
  float* oo = out_o + ((size_t)bb * LQn + q0) * Dn;
  #pragma unroll
  for (int j = 0; j < 4; ++j) {
    int slot = j * NT + t;               // 1024 slots = 64 rows x 16 float4
    int r = slot >> 4, c4 = slot & 15;
    float p = rowP[r];
    int w1 = rW1[r], w2 = rW2[r];
    float4 v1 = *(const float4*)(vb + (size_t)w1 * Dn + c4 * 4);
    float4 o = make_float4(p * v1.x, p * v1.y, p * v1.z, p * v1.w);
    if (w2 >= 0) {
      float4 v2 = *(const float4*)(vb + (size_t)w2 * Dn + c4 * 4);
      o.x += p * v2.x; o.y += p * v2.y; o.z += p * v2.z; o.w += p * v2.w;
    }
    *(float4*)(oo + (size_t)r * Dn + c4 * 4) = o;
  }
}

// ---------------- fallback (proven R1 kernel) if ws too small ---------------
__global__ __launch_bounds__(256, 2)
void attn_wta_fp32(const float* __restrict__ qg, const float* __restrict__ kg,
                   const float* __restrict__ vg, float* __restrict__ out_o,
                   float* __restrict__ out_a) {
  __shared__ float4 k_s[256][16];
  __shared__ float  q_s[64][64];
  float* rowP  = &q_s[0][0];
  int*   rPos1 = (int*)&q_s[1][0];
  int*   rPos2 = (int*)&q_s[2][0];
  const int t = threadIdx.x, tx = t & 31, ty = t >> 5;
  const int wg = (int)blockIdx.x;
  const int swz = (wg & 7) * 64 + (wg >> 3);
  const int bb = swz >> 5, q0 = (swz & 31) * 64;
  const float* qb = qg + ((size_t)bb * LQn + q0) * Dn;
  const float* kb = kg + (size_t)bb * LKn * Dn;
  const float* vb = vg + (size_t)bb * LKn * Dn;
  float* oa = out_a + ((size_t)bb * LQn + q0) * (size_t)LKn;
  float* oo = out_o + ((size_t)bb * LQn + q0) * Dn;
  #pragma unroll
  for (int it = 0; it < 4; ++it) {
    int slot = it * 256 + t, r = slot >> 4, c4 = slot & 15;
    *(float4*)&q_s[r][c4 * 4] = *(const float4*)(qb + r * Dn + c4 * 4);
  }
  float emax[8], e2nd[8], zsum[8]; int pos1[8], pos2[8];
  #pragma unroll
  for (int i = 0; i < 8; ++i) { emax[i] = -1.f; e2nd[i] = -1.f; zsum[i] = 0.f; pos1[i] = 0; pos2[i] = 0; }
  float* zbase = oa + (size_t)(t >> 6) * LKn + (t & 63) * 4;
  #pragma unroll 1
  for (int kt = 0; kt < 8; ++kt) {
    __syncthreads();
    const float* ksrc = kb + (size_t)kt * 256 * Dn;
    #pragma unroll
    for (int it = 0; it < 16; ++it) {
      int slot = it * 256 + t, r = slot >> 4, c4 = slot & 15;
      k_s[r][c4 ^ (r & 7)] = *(const float4*)(ksrc + r * Dn + c4 * 4);
    }
    __syncthreads();
    float4 z4 = make_float4(0.f, 0.f, 0.f, 0.f);
    float* zp = zbase + (size_t)kt * 256;
    #pragma unroll
    for (int it = 0; it < 16; ++it) *(float4*)(zp + (size_t)it * 4 * LKn) = z4;
    float acc[8][8];
    #pragma unroll
    for (int i = 0; i < 8; ++i)
      #pragma unroll
      for (int j = 0; j < 8; ++j) acc[i][j] = 0.f;
    #pragma unroll 4
    for (int dc = 0; dc < 16; ++dc) {
      float4 qv[8], kv[8];
      #pragma unroll
      for (int i = 0; i < 8; ++i) qv[i] = *(const float4*)&q_s[ty * 8 + i][dc * 4];
      const int csw = dc ^ (tx & 7);
      #pragma unroll
      for (int j = 0; j < 8; ++j) kv[j] = k_s[j * 32 + tx][csw];
      #pragma unroll
      for (int i = 0; i < 8; ++i)
        #pragma unroll
        for (int j = 0; j < 8; ++j) {
          acc[i][j] = fmaf(qv[i].x, kv[j].x, acc[i][j]);
          acc[i][j] = fmaf(qv[i].y, kv[j].y, acc[i][j]);
          acc[i][j] = fmaf(qv[i].z, kv[j].z, acc[i][j]);
          acc[i][j] = fmaf(qv[i].w, kv[j].w, acc[i][j]);
        }
    }
    const int kt0 = kt * 256;
    #pragma unroll
    for (int i = 0; i < 8; ++i) {
      float em = emax[i], es = e2nd[i], zq = zsum[i];
      int p1 = pos1[i], p2 = pos2[i];
      #pragma unroll
      for (int j = 0; j < 8; ++j) {
        float e = exp2f(fmaf(acc[i][j], K1, -K2));
        int pos = kt0 + j * 32 + tx;
        bool g1 = e > em, g2 = e > es;
        es = g1 ? em : (g2 ? e : es);
        p2 = g1 ? p1 : (g2 ? pos : p2);
        em = g1 ? e : em;
        p1 = g1 ? pos : p1;
        zq += e;
      }
      emax[i] = em; e2nd[i] = es; zsum[i] = zq; pos1[i] = p1; pos2[i] = p2;
    }
  }
  #pragma unroll
  for (int i = 0; i < 8; ++i) {
    float em = emax[i], es = e2nd[i], zq = zsum[i];
    int p1 = pos1[i], p2 = pos2[i];
    #pragma unroll
    for (int m = 16; m >= 1; m >>= 1) {
      float oem = __shfl_xor(em, m); float oes = __shfl_xor(es, m);
      float ozz = __shfl_xor(zq, m);
      int op1 = __shfl_xor(p1, m); int op2 = __shfl_xor(p2, m);
      zq += ozz;
      bool g1 = oem > em, g2 = oem > es;
      es = g1 ? em : (g2 ? oem : es);
      p2 = g1 ? p1 : (g2 ? op1 : p2);
      em = g1 ? oem : em; p1 = g1 ? op1 : p1;
      bool h2 = oes > es;
      es = h2 ? oes : es; p2 = h2 ? op2 : p2;
    }
    emax[i] = em; e2nd[i] = es; zsum[i] = zq; pos1[i] = p1; pos2[i] = p2;
  }
  __syncthreads();
  if (tx == 0) {
    #pragma unroll
    for (int i = 0; i < 8; ++i) {
      int r = ty * 8 + i;
      float p = emax[i] / zsum[i], p2v = e2nd[i] / zsum[i];
      rowP[r] = p; rPos1[r] = pos1[i]; rPos2[r] = (p2v == p) ? pos2[i] : -1;
    }
  }
  __syncthreads();
  if (t < 64) {
    float p = rowP[t];
    float* ar = oa + (size_t)t * LKn;
    ar[rPos1[t]] = p;
    if (rPos2[t] >= 0) ar[rPos2[t]] = p;
  }
  #pragma unroll
  for (int it = 0; it < 4; ++it) {
    int slot = it * 256 + t, r = slot >> 4, c4 = slot & 15;
    float p = rowP[r];
    int w1 = rPos1[r], w2 = rPos2[r];
    float4 v1 = *(const float4*)(vb + (size_t)w1 * Dn + c4 * 4);
    float4 o = make_float4(p * v1.x, p * v1.y, p * v1.z, p * v1.w);
    if (w2 >= 0) {
      float4 v2 = *(const float4*)(vb + (size_t)w2 * Dn + c4 * 4);
      o.x += p * v2.x; o.y += p * v2.y; o.z += p * v2.z; o.w += p * v2.w;
    }
    *(float4*)(oo + (size_t)r * Dn + c4 * 4) = o;
  }
}

extern "C" void kernel_launch(void* const* d_in, const int* in_sizes, int n_in,
                              void* d_out, int out_size, void* d_ws, size_t ws_size,
                              hipStream_t stream) {
  const float* q = (const float*)d_in[0];
  const float* k = (const float*)d_in[1];
  const float* v = (const float*)d_in[2];
  float* out_o = (float*)d_out;                                  // [16,2048,64]
  float* out_a = (float*)d_out + (size_t)16 * 2048 * 64;         // [16,2048,2048]
  if (ws_size >= (size_t)8388608) {
    half8* khl = (half8*)d_ws;                                   // 8 MB
    hipLaunchKernelGGL(split_pack_k, dim3(256), dim3(256), 0, stream, k, khl);
    hipLaunchKernelGGL(attn_wta_mfma, dim3(512), dim3(NT), 0, stream,
                       q, khl, v, out_o, out_a);
  } else {
    hipLaunchKernelGGL(attn_wta_fp32, dim3(512), dim3(256), 0, stream,
                       q, k, v, out_o, out_a);
  }
}